// Round 10
// baseline (182.267 us; speedup 1.0000x reference)
//
#include <hip/hip_runtime.h>
#include <hip/hip_bf16.h>

typedef unsigned int u32;
typedef unsigned long long u64;

#define BB 16
#define NA 5
#define NC 20
#define HF 19
#define WF 19
#define NPIX 361        // 19*19
#define NB 1805         // NA*NPIX boxes per batch
#define NW32 58         // ceil(1805/32)
#define NW64 29         // ceil(1805/64)
#define MS64 32         // padded M row stride in u64 (256 B rows)
#define MS32 64         // padded M row stride in u32
#define NBC (BB*NC)     // 320 (batch,class) pairs
#define PROB_ELEMS (BB*NB*NC)   // 577600
#define NCHUNK 29       // ceil(NB/64)
#define IOUQ 8
#define IOUG 226        // ceil(NB/IOUQ)
#define IOUBLK 29       // ceil(IOUG/8) blocks per batch in fused kernel

// Exact-equivalence threshold: RN_f32(inter/denom) > 0.45f
//   <=>  (double)inter > MID * (double)denom
// where MID = midpoint(0.45f, nextup(0.45f)) = 0x1.CCCCCDp-2 (exact in f64;
// 25-bit MID x 24-bit denom product is exact; tie rounds-to-even to 0.45f
// which is NOT > 0.45f, matching the strict > here).
#define IOU_MID 0x1.CCCCCDp-2

__constant__ float c_bias[10] = {1.08f, 1.19f, 3.42f, 4.41f, 6.63f,
                                 11.38f, 9.42f, 5.11f, 16.62f, 10.52f};

__device__ __forceinline__ float sigmoidf_(float v) {
    return 1.0f / (1.0f + expf(-v));
}

// ---------------------------------------------------------------------------
// Kernel 1: decode boxes (-> d_out boxes section), corners+areas, scores.
// ---------------------------------------------------------------------------
__global__ __launch_bounds__(256) void decode_kernel(
        const float* __restrict__ x, const float* __restrict__ im_info,
        float* __restrict__ boxes_out, float4* __restrict__ corners,
        float* __restrict__ areas, float* __restrict__ scores) {
    int tid = blockIdx.x * blockDim.x + threadIdx.x;
    if (tid >= BB * NB) return;
    int b = tid / NB;
    int n = tid % NB;
    int a = n / NPIX;
    int r = n % NPIX;
    int gy = r / WF;
    int gx = r % WF;

    const float* xb = x + (size_t)b * 125 * NPIX + r;   // channel stride NPIX
    float tx = xb[(2 * a + 0) * NPIX];
    float ty = xb[(2 * a + 1) * NPIX];
    float tw = xb[(10 + 2 * a) * NPIX];
    float th = xb[(11 + 2 * a) * NPIX];
    float to = xb[(20 + a) * NPIX];

    float sx = sigmoidf_(tx);
    float sy = sigmoidf_(ty);
    float obj = sigmoidf_(to);

    float im_h = im_info[b * 2 + 0];
    float im_w = im_info[b * 2 + 1];

    float bx = ((sx + (float)gx) / (float)WF) * im_w;
    float by = ((sy + (float)gy) / (float)HF) * im_h;
    float bw = ((expf(tw) * c_bias[2 * a + 0]) / (float)WF) * im_w;
    float bh = ((expf(th) * c_bias[2 * a + 1]) / (float)HF) * im_h;

    reinterpret_cast<float4*>(boxes_out)[tid] = make_float4(bx, by, bw, bh);

    // corners exactly as reference computes them from (cx,cy,w,h)
    float x1 = bx - bw * 0.5f, x2 = bx + bw * 0.5f;
    float y1 = by - bh * 0.5f, y2 = by + bh * 0.5f;
    corners[tid] = make_float4(x1, y1, x2, y2);
    areas[tid] = bw * bh;

    // softmax over 20 classes * obj  -> scores[(b*NC + c)*NB + n]
    float cv[NC];
    float m = -1e30f;
    #pragma unroll
    for (int c = 0; c < NC; ++c) {
        cv[c] = xb[(25 + NC * a + c) * NPIX];
        m = fmaxf(m, cv[c]);
    }
    float sum = 0.0f;
    #pragma unroll
    for (int c = 0; c < NC; ++c) {
        cv[c] = expf(cv[c] - m);
        sum += cv[c];
    }
    #pragma unroll
    for (int c = 0; c < NC; ++c) {
        scores[((size_t)b * NC + c) * NB + n] = (cv[c] / sum) * obj;
    }
}

// ---------------------------------------------------------------------------
// Fused kernel 2: blocks [0, NBC) run the bitonic argsort; blocks
// [NBC, NBC + BB*IOUBLK) run the IoU bitmask (8 independent waves per block,
// 8 rows per wave, software-pipelined column loads).  Independent inputs
// (scores vs corners) -> co-resident waves overlap the two phases.
// ---------------------------------------------------------------------------
__device__ __forceinline__ u64 shfl_xor_u64(u64 v, int m) {
    u32 lo = (u32)v, hi = (u32)(v >> 32);
    lo = (u32)__shfl_xor((int)lo, m, 64);
    hi = (u32)__shfl_xor((int)hi, m, 64);
    return ((u64)hi << 32) | lo;
}

__device__ void sort_body(const float* __restrict__ scores,
                          u32* __restrict__ order, int bc) {
    __shared__ u64 keys[2048];
    const float* s = scores + (size_t)bc * NB;
    int tid = threadIdx.x;
    int lane = tid & 63;
    int w = tid >> 6;
    int base = w * 256;

    u64 r[4];
    #pragma unroll
    for (int i = 0; i < 4; ++i) {
        int e = base + i * 64 + lane;
        u64 k = 0;
        if (e < NB) {
            u32 sb = __float_as_uint(s[e]);
            k = ((u64)sb << 32) | (u64)(2047 - e);
        }
        r[i] = k;
    }

    auto rexch = [&](int k, int ia, int ib) {
        int e = base + ia * 64 + lane;           // lower element index
        bool desc = ((e & k) == 0);
        u64 a = r[ia], b = r[ib];
        u64 mx = a > b ? a : b, mn = a > b ? b : a;
        r[ia] = desc ? mx : mn;
        r[ib] = desc ? mn : mx;
    };
    auto shstage = [&](int k, int j) {
        #pragma unroll
        for (int i = 0; i < 4; ++i) {
            int e = base + i * 64 + lane;
            u64 p = shfl_xor_u64(r[i], j);
            bool desc = ((e & k) == 0);
            bool upper = (lane & j) != 0;
            bool takemax = desc ^ upper;
            u64 a = r[i];
            u64 mx = a > p ? a : p, mn = a > p ? p : a;
            r[i] = takemax ? mx : mn;
        }
    };
    auto regsession = [&](int k) {
        if (k >= 256) { rexch(k, 0, 2); rexch(k, 1, 3); }   // j=128
        if (k >= 128) { rexch(k, 0, 1); rexch(k, 2, 3); }   // j=64
        int j0 = (k <= 64) ? (k >> 1) : 32;
        for (int j = j0; j >= 1; j >>= 1) shstage(k, j);
    };
    auto store_regs = [&]() {
        #pragma unroll
        for (int i = 0; i < 4; ++i) keys[base + i * 64 + lane] = r[i];
    };
    auto load_regs = [&]() {
        #pragma unroll
        for (int i = 0; i < 4; ++i) r[i] = keys[base + i * 64 + lane];
    };
    auto ldspass = [&](int k, int j) {
        #pragma unroll
        for (int h = 0; h < 2; ++h) {
            int m = tid + h * 512;
            int i1 = (m / j) * 2 * j + (m % j);
            int i2 = i1 + j;
            u64 a = keys[i1], b = keys[i2];
            bool desc = ((i1 & k) == 0);
            bool sw = desc ? (a < b) : (a > b);
            if (sw) { keys[i1] = b; keys[i2] = a; }
        }
        __syncthreads();
    };

    for (int k = 2; k <= 256; k <<= 1) regsession(k);
    store_regs(); __syncthreads();

    ldspass(512, 256);
    load_regs(); regsession(512);
    store_regs(); __syncthreads();

    ldspass(1024, 512); ldspass(1024, 256);
    load_regs(); regsession(1024);
    store_regs(); __syncthreads();

    ldspass(2048, 1024); ldspass(2048, 512); ldspass(2048, 256);
    load_regs(); regsession(2048);

    #pragma unroll
    for (int i = 0; i < 4; ++i) {
        int e = base + i * 64 + lane;
        if (e < NB)
            order[(size_t)bc * NB + e] = 2047u - (u32)(r[i] & 0xFFFFFFFFull);
    }
}

__device__ void iou_body(const float4* __restrict__ corners,
                         const float* __restrict__ areas,
                         u64* __restrict__ M64, int b, int i0) {
    int lane = threadIdx.x & 63;
    const float4* cb = corners + (size_t)b * NB;
    const float* ab = areas + (size_t)b * NB;

    float4 cr[IOUQ];
    float arr[IOUQ];
    #pragma unroll
    for (int q = 0; q < IOUQ; ++q) {
        int iq = i0 + q < NB ? i0 + q : NB - 1;
        cr[q] = cb[iq];
        arr[q] = ab[iq];
    }

    u64 word[IOUQ] = {0, 0, 0, 0, 0, 0, 0, 0};
    // software-pipelined column loads (depth 1): hide L1/L2 latency behind
    // the 8-row compute block
    float4 cj = cb[lane];              // t=0: j = lane < NB always
    float ar = ab[lane];
    for (int t = 0; t < NW64; ++t) {
        int j = t * 64 + lane;
        float4 cjn = cj;
        float arn = ar;
        if (t + 1 < NW64) {
            int j2 = (t + 1) * 64 + lane;
            int jc2 = j2 < NB ? j2 : NB - 1;
            cjn = cb[jc2];
            arn = ab[jc2];
        }
        #pragma unroll
        for (int q = 0; q < IOUQ; ++q) {
            float iw = fmaxf(fminf(cr[q].z, cj.z) - fmaxf(cr[q].x, cj.x), 0.0f);
            float ih = fmaxf(fminf(cr[q].w, cj.w) - fmaxf(cr[q].y, cj.y), 0.0f);
            float in = iw * ih;
            float dn = arr[q] + ar - in + 1e-9f;
            bool p = ((double)in > IOU_MID * (double)dn) && (j < NB);
            u64 m = __ballot(p);
            if (lane == t) word[q] = m;
        }
        cj = cjn;
        ar = arn;
    }
    if (lane < MS64) {
        #pragma unroll
        for (int q = 0; q < IOUQ; ++q) {
            int iq = i0 + q;
            if (iq < NB) {
                u64 w = (lane < NW64) ? word[q] : 0ull;
                M64[((size_t)b * NB + iq) * MS64 + lane] = w;
            }
        }
    }
}

__global__ __launch_bounds__(512) void work_kernel(
        const float* __restrict__ scores, u32* __restrict__ order,
        const float4* __restrict__ corners, const float* __restrict__ areas,
        u64* __restrict__ M64) {
    int blk = blockIdx.x;
    if (blk < NBC) {
        sort_body(scores, order, blk);
    } else {
        int ib = blk - NBC;            // 0 .. BB*IOUBLK-1
        int b = ib / IOUBLK;
        int gset = ib % IOUBLK;
        int wid = threadIdx.x >> 6;
        int group = gset * 8 + wid;    // 8 row-groups per block
        if (group < IOUG) iou_body(corners, areas, M64, b, group * IOUQ);
    }
}

// ---------------------------------------------------------------------------
// Kernel 3: per-(b,c,chunk) 64x64 column masks, one wave per chunk-mask.
// colm[bc][p] (u64): bit d = M[idx_d][idx_p].  Direct per-lane gather:
// 2x32 INDEPENDENT loads batched into registers (one vmcnt drain each),
// then pure VALU bit extraction — no load->ballot serialization.
// 9280 waves -> latency fully hidden.
// ---------------------------------------------------------------------------
__global__ __launch_bounds__(64) void colmask_kernel(
        const u32* __restrict__ order, const u32* __restrict__ M32,
        u64* __restrict__ colm) {
    int blk = blockIdx.x;              // NBC * NCHUNK
    int t = blk % NBC;                 // same (b,cls) mapping as nms kernel
    int ch = blk / NBC;
    int b = t % BB;                    // XCD-cluster batches for M L2 locality
    int cls = t / BB;
    int bc = b * NC + cls;
    int lane = threadIdx.x;
    const u32* ord = order + (size_t)bc * NB;
    const u32* Mb = M32 + (size_t)b * NB * MS32;

    int p = ch * 64 + lane;
    u32 idx = (p < NB) ? ord[p] : (u32)(NB - 1);
    u32 we = idx >> 5, be = idx & 31u;

    u32 collo = 0, colhi = 0;
    {
        u32 wreg[32];
        #pragma unroll
        for (int d = 0; d < 32; ++d) {
            u32 idxd = (u32)__builtin_amdgcn_readlane((int)idx, d);
            wreg[d] = Mb[(size_t)idxd * MS32 + we];
        }
        #pragma unroll
        for (int d = 0; d < 32; ++d)
            collo |= ((wreg[d] >> be) & 1u) << d;
    }
    {
        u32 wreg[32];
        #pragma unroll
        for (int d = 0; d < 32; ++d) {
            u32 idxd = (u32)__builtin_amdgcn_readlane((int)idx, d + 32);
            wreg[d] = Mb[(size_t)idxd * MS32 + we];
        }
        #pragma unroll
        for (int d = 0; d < 32; ++d)
            colhi |= ((wreg[d] >> be) & 1u) << d;
    }
    colm[(size_t)bc * (NCHUNK * 64) + p] = ((u64)colhi << 32) | (u64)collo;
}

// ---------------------------------------------------------------------------
// Kernel 4: greedy NMS + prob write, ONE WAVE per (b,c)  [R7 structure —
// measured-best scan].  Column masks precomputed (8B coalesced register-
// prefetched loads, 2 chunks ahead).  Per chunk: bpermute pre-check ->
// exact greedy ballot rounds -> gated-OR fold of LDS-staged rows (skipped
// when kept==0).  Staging: 16 width-16 global_load_lds (4 rows/inst),
// double-buffered, indices from LDS-resident sorted order.
// Epilogue: prob[b][n][cls] written from LDS keep bits (kills the finalize
// dispatch).  blockIdx: b = blk % 16 clusters same-batch blocks per XCD.
// ---------------------------------------------------------------------------
__global__ __launch_bounds__(64, 1) void nms_scan_kernel(
        const u32* __restrict__ order, const u32* __restrict__ M32,
        const u64* __restrict__ colm, const float* __restrict__ scores,
        float* __restrict__ prob) {
    int blk = blockIdx.x;
    int b = blk % BB;            // blk%8 = XCD -> 2 batches per XCD (L2 locality)
    int cls = blk / BB;
    int bc = b * NC + cls;
    int lane = threadIdx.x;
    const u32* ord = order + (size_t)bc * NB;
    const u32* Mb = M32 + (size_t)b * NB * MS32;
    const u64* colmb = colm + (size_t)bc * (NCHUNK * 64);

    __shared__ u32 rows[2][64 * 64];   // [buf][row d][word], 32 KB
    __shared__ u32 sord[NCHUNK * 64];  // 1856 sorted indices (clamped), 7.4 KB
    __shared__ u32 kws[64];
    kws[lane] = 0;

    for (int t = lane; t < NCHUNK * 64; t += 64)
        sord[t] = (t < NB) ? ord[t] : (u32)(NB - 1);
    __syncthreads();

    int sub = lane >> 4;               // row-within-group for staging
    int l16 = lane & 15;

    // stage chunk 0 into buffer 0: 16 idx ds_reads (one wait) + 16 glls
    {
        u32 ridx[16];
        #pragma unroll
        for (int t = 0; t < 16; ++t) ridx[t] = sord[t * 4 + sub];
        #pragma unroll
        for (int t = 0; t < 16; ++t) {
            const u32* rowp = Mb + (size_t)ridx[t] * MS32 + l16 * 4;
            __builtin_amdgcn_global_load_lds(
                (const __attribute__((address_space(1))) void*)rowp,
                (__attribute__((address_space(3))) void*)&rows[0][t * 256],
                16, 0, 0);
        }
    }
    u64 colv_cur = colmb[lane];        // chunk 0 colmask
    u64 colv_nx = colmb[64 + lane];    // chunk 1 colmask
    __syncthreads();                   // drains chunk-0 staging

    u64 lt = (1ull << lane) - 1ull;    // bits strictly below my candidate slot
    u32 rw = 0;                        // removed word (lane w owns word w)

    int cur = 0;
    for (int c = 0; c < NCHUNK; ++c) {
        // stage chunk c+1 rows into the other buffer (off the chain)
        if (c + 1 < NCHUNK) {
            u32 ridx[16];
            #pragma unroll
            for (int t = 0; t < 16; ++t)
                ridx[t] = sord[(c + 1) * 64 + t * 4 + sub];
            #pragma unroll
            for (int t = 0; t < 16; ++t) {
                const u32* rowp = Mb + (size_t)ridx[t] * MS32 + l16 * 4;
                __builtin_amdgcn_global_load_lds(
                    (const __attribute__((address_space(1))) void*)rowp,
                    (__attribute__((address_space(3))) void*)&rows[cur ^ 1][t * 256],
                    16, 0, 0);
            }
        }
        // register prefetch of chunk c+2 colmask
        u64 colv_nx2 = colv_nx;
        if (c + 2 < NCHUNK) colv_nx2 = colmb[(c + 2) * 64 + lane];

        u32 idx = sord[c * 64 + lane];
        u32 we = idx >> 5;
        u32 be = idx & 31u;
        bool valid = (c * 64 + lane) < NB;

        // pre-suppression: bit idx of removed mask (word we on lane we)
        u32 wv = (u32)__builtin_amdgcn_ds_bpermute((int)(we << 2), (int)rw);
        bool pre = ((wv >> be) & 1u) != 0u;

        u64 col = colv_cur;

        // exact greedy via ballot rounds (rounds = chain depth)
        u64 act = __ballot(valid && !pre);
        u64 kept = 0;
        while (act) {
            u64 unsafe = __ballot((col & act & lt) != 0ull);
            u64 safe = act & ~unsafe;           // provably greedy-kept
            kept |= safe;
            u64 supp = __ballot((col & safe & lt) != 0ull);
            act &= ~(safe | supp);
        }

        if ((kept >> lane) & 1ull) atomicOr(&kws[we], 1u << be);

        // fold kept rows into removed mask: branchless gated OR over staged
        // rows (pad words 58..63 are zero in M); skipped when kept==0
        if (kept != 0ull) {
            const u32* rbase = &rows[cur][0];
            u32 klo = (u32)kept, khi = (u32)(kept >> 32);
            #pragma unroll
            for (int d = 0; d < 32; ++d)
                rw |= rbase[d * 64 + lane] & (0u - ((klo >> d) & 1u));
            #pragma unroll
            for (int d = 0; d < 32; ++d)
                rw |= rbase[(d + 32) * 64 + lane] & (0u - ((khi >> d) & 1u));
        }

        __syncthreads();   // drains staging of chunk c+1; orders buffer reuse
        cur ^= 1;
        colv_cur = colv_nx;
        colv_nx = colv_nx2;
    }
    __syncthreads();       // kws final

    // fused finalize: prob[b][n][cls] = keep ? score : 0
    const float* sc = scores + (size_t)bc * NB;
    float* pb = prob + (size_t)b * NB * NC + cls;
    for (int n = lane; n < NB; n += 64) {
        u32 w = kws[n >> 5];
        float v = ((w >> (n & 31)) & 1u) ? sc[n] : 0.0f;
        pb[(size_t)n * NC] = v;
    }
}

// ---------------------------------------------------------------------------
extern "C" void kernel_launch(void* const* d_in, const int* in_sizes, int n_in,
                              void* d_out, int out_size, void* d_ws, size_t ws_size,
                              hipStream_t stream) {
    const float* x = (const float*)d_in[0];        // (16,125,19,19)
    const float* im_info = (const float*)d_in[1];  // (16,2)

    float* prob_out = (float*)d_out;                       // 577600 floats
    float* boxes_out = prob_out + PROB_ELEMS;              // 115520 floats

    // workspace layout (corners/areas DISJOINT from order: sort and iou run
    // concurrently in the fused kernel)
    float* scores = (float*)d_ws;                           // 577600 f32
    u32* order = (u32*)(scores + PROB_ELEMS);               // 577600 u32
    char* mbase = (char*)d_ws + (size_t)2 * PROB_ELEMS * 4;
    u64* M64 = (u64*)mbase;                                 // 16*1805*32 u64 (padded)
    u32* M32 = (u32*)mbase;
    char* cbase = mbase + (size_t)BB * NB * MS64 * 8;
    float4* corners = (float4*)cbase;                       // 28880 float4
    float* areas = (float*)(corners + (size_t)BB * NB);     // 28880 f32
    u64* colm = (u64*)(cbase + (size_t)BB * NB * 20 + 256); // 320*1856 u64

    int nthreads = BB * NB;   // 28880
    decode_kernel<<<(nthreads + 255) / 256, 256, 0, stream>>>(
        x, im_info, boxes_out, corners, areas, scores);

    work_kernel<<<NBC + BB * IOUBLK, 512, 0, stream>>>(
        scores, order, corners, areas, M64);

    colmask_kernel<<<NBC * NCHUNK, 64, 0, stream>>>(order, M32, colm);

    nms_scan_kernel<<<NBC, 64, 0, stream>>>(order, M32, colm, scores, prob_out);
}

// Round 11
// 173.085 us; speedup vs baseline: 1.0530x; 1.0530x over previous
//
#include <hip/hip_runtime.h>
#include <hip/hip_bf16.h>

typedef unsigned int u32;
typedef unsigned long long u64;
typedef unsigned char u8;

#define BB 16
#define NA 5
#define NC 20
#define HF 19
#define WF 19
#define NPIX 361        // 19*19
#define NB 1805         // NA*NPIX boxes per batch
#define NW32 58         // ceil(1805/32)
#define NW64 29         // ceil(1805/64)
#define MS64 32         // padded M row stride in u64 (256 B rows)
#define MS32 64         // padded M row stride in u32
#define NBC (BB*NC)     // 320 (batch,class) pairs
#define PROB_ELEMS (BB*NB*NC)   // 577600
#define NCHUNK 29       // ceil(NB/64)
#define IOUQ 8
#define IOUG 226        // ceil(NB/IOUQ)
#define IOUBLK 29       // ceil(IOUG/8) blocks per batch in fused kernel

// Exact-equivalence threshold: RN_f32(inter/denom) > 0.45f
//   <=>  (double)inter > MID * (double)denom
// where MID = midpoint(0.45f, nextup(0.45f)) = 0x1.CCCCCDp-2 (exact in f64;
// 25-bit MID x 24-bit denom product is exact; tie rounds-to-even to 0.45f
// which is NOT > 0.45f, matching the strict > here).
#define IOU_MID 0x1.CCCCCDp-2

__constant__ float c_bias[10] = {1.08f, 1.19f, 3.42f, 4.41f, 6.63f,
                                 11.38f, 9.42f, 5.11f, 16.62f, 10.52f};

__device__ __forceinline__ float sigmoidf_(float v) {
    return 1.0f / (1.0f + expf(-v));
}

// ---------------------------------------------------------------------------
// Kernel 1: decode boxes (-> d_out boxes section), corners+areas, scores.
// ---------------------------------------------------------------------------
__global__ __launch_bounds__(256) void decode_kernel(
        const float* __restrict__ x, const float* __restrict__ im_info,
        float* __restrict__ boxes_out, float4* __restrict__ corners,
        float* __restrict__ areas, float* __restrict__ scores) {
    int tid = blockIdx.x * blockDim.x + threadIdx.x;
    if (tid >= BB * NB) return;
    int b = tid / NB;
    int n = tid % NB;
    int a = n / NPIX;
    int r = n % NPIX;
    int gy = r / WF;
    int gx = r % WF;

    const float* xb = x + (size_t)b * 125 * NPIX + r;   // channel stride NPIX
    float tx = xb[(2 * a + 0) * NPIX];
    float ty = xb[(2 * a + 1) * NPIX];
    float tw = xb[(10 + 2 * a) * NPIX];
    float th = xb[(11 + 2 * a) * NPIX];
    float to = xb[(20 + a) * NPIX];

    float sx = sigmoidf_(tx);
    float sy = sigmoidf_(ty);
    float obj = sigmoidf_(to);

    float im_h = im_info[b * 2 + 0];
    float im_w = im_info[b * 2 + 1];

    float bx = ((sx + (float)gx) / (float)WF) * im_w;
    float by = ((sy + (float)gy) / (float)HF) * im_h;
    float bw = ((expf(tw) * c_bias[2 * a + 0]) / (float)WF) * im_w;
    float bh = ((expf(th) * c_bias[2 * a + 1]) / (float)HF) * im_h;

    reinterpret_cast<float4*>(boxes_out)[tid] = make_float4(bx, by, bw, bh);

    // corners exactly as reference computes them from (cx,cy,w,h)
    float x1 = bx - bw * 0.5f, x2 = bx + bw * 0.5f;
    float y1 = by - bh * 0.5f, y2 = by + bh * 0.5f;
    corners[tid] = make_float4(x1, y1, x2, y2);
    areas[tid] = bw * bh;

    // softmax over 20 classes * obj  -> scores[(b*NC + c)*NB + n]
    float cv[NC];
    float m = -1e30f;
    #pragma unroll
    for (int c = 0; c < NC; ++c) {
        cv[c] = xb[(25 + NC * a + c) * NPIX];
        m = fmaxf(m, cv[c]);
    }
    float sum = 0.0f;
    #pragma unroll
    for (int c = 0; c < NC; ++c) {
        cv[c] = expf(cv[c] - m);
        sum += cv[c];
    }
    #pragma unroll
    for (int c = 0; c < NC; ++c) {
        scores[((size_t)b * NC + c) * NB + n] = (cv[c] / sum) * obj;
    }
}

// ---------------------------------------------------------------------------
// Fused kernel 2: blocks [0, NBC) run the bitonic argsort; blocks
// [NBC, NBC + BB*IOUBLK) run the IoU bitmask.
// IoU now exploits EXACT SYMMETRY (min/max/mul/add all commutative in f32,
// so IoU(i,j) is bit-identical to IoU(j,i)): each 8-row group only computes
// column blocks t >= its own block Bg; the mirrored entries are produced by
// byte-granular transpose stores (8-row group <-> one byte of the u64 word).
// Mirror writes target words < B_row; direct writes cover words >= B_row —
// provably disjoint, full coverage, no races.
// ---------------------------------------------------------------------------
__device__ __forceinline__ u64 shfl_xor_u64(u64 v, int m) {
    u32 lo = (u32)v, hi = (u32)(v >> 32);
    lo = (u32)__shfl_xor((int)lo, m, 64);
    hi = (u32)__shfl_xor((int)hi, m, 64);
    return ((u64)hi << 32) | lo;
}

__device__ void sort_body(const float* __restrict__ scores,
                          u32* __restrict__ order, int bc) {
    __shared__ u64 keys[2048];
    const float* s = scores + (size_t)bc * NB;
    int tid = threadIdx.x;
    int lane = tid & 63;
    int w = tid >> 6;
    int base = w * 256;

    u64 r[4];
    #pragma unroll
    for (int i = 0; i < 4; ++i) {
        int e = base + i * 64 + lane;
        u64 k = 0;
        if (e < NB) {
            u32 sb = __float_as_uint(s[e]);
            k = ((u64)sb << 32) | (u64)(2047 - e);
        }
        r[i] = k;
    }

    auto rexch = [&](int k, int ia, int ib) {
        int e = base + ia * 64 + lane;           // lower element index
        bool desc = ((e & k) == 0);
        u64 a = r[ia], b = r[ib];
        u64 mx = a > b ? a : b, mn = a > b ? b : a;
        r[ia] = desc ? mx : mn;
        r[ib] = desc ? mn : mx;
    };
    auto shstage = [&](int k, int j) {
        #pragma unroll
        for (int i = 0; i < 4; ++i) {
            int e = base + i * 64 + lane;
            u64 p = shfl_xor_u64(r[i], j);
            bool desc = ((e & k) == 0);
            bool upper = (lane & j) != 0;
            bool takemax = desc ^ upper;
            u64 a = r[i];
            u64 mx = a > p ? a : p, mn = a > p ? p : a;
            r[i] = takemax ? mx : mn;
        }
    };
    auto regsession = [&](int k) {
        if (k >= 256) { rexch(k, 0, 2); rexch(k, 1, 3); }   // j=128
        if (k >= 128) { rexch(k, 0, 1); rexch(k, 2, 3); }   // j=64
        int j0 = (k <= 64) ? (k >> 1) : 32;
        for (int j = j0; j >= 1; j >>= 1) shstage(k, j);
    };
    auto store_regs = [&]() {
        #pragma unroll
        for (int i = 0; i < 4; ++i) keys[base + i * 64 + lane] = r[i];
    };
    auto load_regs = [&]() {
        #pragma unroll
        for (int i = 0; i < 4; ++i) r[i] = keys[base + i * 64 + lane];
    };
    auto ldspass = [&](int k, int j) {
        #pragma unroll
        for (int h = 0; h < 2; ++h) {
            int m = tid + h * 512;
            int i1 = (m / j) * 2 * j + (m % j);
            int i2 = i1 + j;
            u64 a = keys[i1], b = keys[i2];
            bool desc = ((i1 & k) == 0);
            bool sw = desc ? (a < b) : (a > b);
            if (sw) { keys[i1] = b; keys[i2] = a; }
        }
        __syncthreads();
    };

    for (int k = 2; k <= 256; k <<= 1) regsession(k);
    store_regs(); __syncthreads();

    ldspass(512, 256);
    load_regs(); regsession(512);
    store_regs(); __syncthreads();

    ldspass(1024, 512); ldspass(1024, 256);
    load_regs(); regsession(1024);
    store_regs(); __syncthreads();

    ldspass(2048, 1024); ldspass(2048, 512); ldspass(2048, 256);
    load_regs(); regsession(2048);

    #pragma unroll
    for (int i = 0; i < 4; ++i) {
        int e = base + i * 64 + lane;
        if (e < NB)
            order[(size_t)bc * NB + e] = 2047u - (u32)(r[i] & 0xFFFFFFFFull);
    }
}

__device__ void iou_body(const float4* __restrict__ corners,
                         const float* __restrict__ areas,
                         u64* __restrict__ M64, int b, int i0) {
    int lane = threadIdx.x & 63;
    const float4* cb = corners + (size_t)b * NB;
    const float* ab = areas + (size_t)b * NB;
    int Bg = i0 >> 6;                  // this group's column block (triangle)
    int byteoff = (i0 & 63) >> 3;      // byte slot of this 8-row group
    u8* M8 = (u8*)M64;

    float4 cr[IOUQ];
    float arr[IOUQ];
    #pragma unroll
    for (int q = 0; q < IOUQ; ++q) {
        int iq = i0 + q < NB ? i0 + q : NB - 1;
        cr[q] = cb[iq];
        arr[q] = ab[iq];
    }

    u64 word[IOUQ] = {0, 0, 0, 0, 0, 0, 0, 0};
    // software-pipelined column loads (depth 1), t starts at Bg (triangle)
    int jp = Bg * 64 + lane;
    int jpc = jp < NB ? jp : NB - 1;
    float4 cj = cb[jpc];
    float ar = ab[jpc];
    for (int t = Bg; t < NW64; ++t) {
        int j = t * 64 + lane;
        float4 cjn = cj;
        float arn = ar;
        if (t + 1 < NW64) {
            int j2 = (t + 1) * 64 + lane;
            int jc2 = j2 < NB ? j2 : NB - 1;
            cjn = cb[jc2];
            arn = ab[jc2];
        }
        u64 mv[IOUQ];
        #pragma unroll
        for (int q = 0; q < IOUQ; ++q) {
            float iw = fmaxf(fminf(cr[q].z, cj.z) - fmaxf(cr[q].x, cj.x), 0.0f);
            float ih = fmaxf(fminf(cr[q].w, cj.w) - fmaxf(cr[q].y, cj.y), 0.0f);
            float in = iw * ih;
            float dn = arr[q] + ar - in + 1e-9f;
            bool p = ((double)in > IOU_MID * (double)dn) && (j < NB);
            u64 m = __ballot(p);
            mv[q] = m;
            if (lane == t) word[q] = m;
        }
        // mirror: byte for row j's word Bg (bits q = this group's 8 rows).
        // Exact symmetry makes this bit-identical to the direct value.
        if (t > Bg && j < NB) {
            u32 byt = 0;
            #pragma unroll
            for (int q = 0; q < IOUQ; ++q)
                byt |= ((u32)((mv[q] >> lane) & 1ull)) << q;
            M8[(((size_t)b * NB + j) * MS64 + Bg) * 8 + byteoff] = (u8)byt;
        }
        cj = cjn;
        ar = arn;
    }
    // direct writes: words [Bg..28] values, [29..31] zero; words < Bg are
    // owned by other groups' mirror bytes.
    if (lane >= Bg && lane < MS64) {
        #pragma unroll
        for (int q = 0; q < IOUQ; ++q) {
            int iq = i0 + q;
            if (iq < NB) {
                u64 w = (lane < NW64) ? word[q] : 0ull;
                M64[((size_t)b * NB + iq) * MS64 + lane] = w;
            }
        }
    }
}

__global__ __launch_bounds__(512) void work_kernel(
        const float* __restrict__ scores, u32* __restrict__ order,
        const float4* __restrict__ corners, const float* __restrict__ areas,
        u64* __restrict__ M64) {
    int blk = blockIdx.x;
    if (blk < NBC) {
        sort_body(scores, order, blk);
    } else {
        int ib = blk - NBC;            // 0 .. BB*IOUBLK-1
        int b = ib / IOUBLK;
        int gset = ib % IOUBLK;
        int wid = threadIdx.x >> 6;
        int group = gset * 8 + wid;    // 8 row-groups per block
        if (group < IOUG) iou_body(corners, areas, M64, b, group * IOUQ);
    }
}

// ---------------------------------------------------------------------------
// Kernel 3: greedy NMS + prob write, one block (4 waves) per (b,c).
// [R9 structure — measured best total]  Prepass: 4 waves build all 29 chunk
// colmasks in LDS via direct per-lane column gather (2x32 independent loads
// into registers, then VALU bit extraction).  Main loop: wave 1 stages
// chunk c+1 rows (width-16 global_load_lds); wave 0 runs the serial chain:
// bpermute pre-check -> exact greedy ballot rounds -> gated-OR fold (skipped
// when kept==0).  Epilogue: all 4 waves write prob[b][n][cls] from LDS keep
// bits.  blockIdx: b = blk % 16 clusters same-batch blocks per XCD.
// ---------------------------------------------------------------------------
__global__ __launch_bounds__(256) void nms_scan_kernel(
        const u32* __restrict__ order, const u32* __restrict__ M32,
        const float* __restrict__ scores, float* __restrict__ prob) {
    int blk = blockIdx.x;
    int b = blk % BB;            // blk%8 = XCD -> 2 batches per XCD (L2 locality)
    int cls = blk / BB;
    int bc = b * NC + cls;
    int tid = threadIdx.x;
    int wid = tid >> 6;
    int lane = tid & 63;
    const u32* ord = order + (size_t)bc * NB;
    const u32* Mb = M32 + (size_t)b * NB * MS32;

    __shared__ u32 rows[2][64 * 64];   // [buf][row d][word], 32 KB
    __shared__ u32 sord[NCHUNK * 64];  // 1856 sorted indices (clamped), 7.4 KB
    __shared__ u64 colmL[NCHUNK * 64]; // per-chunk 64x64 colmasks, 14.8 KB
    __shared__ u32 kws[64];
    if (tid < 64) kws[tid] = 0;

    for (int t = tid; t < NCHUNK * 64; t += 256)
        sord[t] = (t < NB) ? ord[t] : (u32)(NB - 1);
    __syncthreads();

    int sub = lane >> 4;               // row-within-group for staging
    int l16 = lane & 15;

    // wave 1: stage chunk 0 rows first (glls overlap the prepass below)
    if (wid == 1) {
        u32 ridx[16];
        #pragma unroll
        for (int t = 0; t < 16; ++t) ridx[t] = sord[t * 4 + sub];
        #pragma unroll
        for (int t = 0; t < 16; ++t) {
            const u32* rowp = Mb + (size_t)ridx[t] * MS32 + l16 * 4;
            __builtin_amdgcn_global_load_lds(
                (const __attribute__((address_space(1))) void*)rowp,
                (__attribute__((address_space(3))) void*)&rows[0][t * 256],
                16, 0, 0);
        }
    }

    // cooperative colmask prepass: wave w handles chunks w, w+4, ...
    // Direct gather: lane e loads word we_e of row idx_d for d=0..63 —
    // 2x32 INDEPENDENT loads batched into registers, then VALU extraction.
    for (int ch = wid; ch < NCHUNK; ch += 4) {
        u32 idx = sord[ch * 64 + lane];
        u32 we = idx >> 5, be = idx & 31u;
        u32 collo = 0, colhi = 0;
        {
            u32 wreg[32];
            #pragma unroll
            for (int d = 0; d < 32; ++d) {
                u32 idxd = (u32)__builtin_amdgcn_readlane((int)idx, d);
                wreg[d] = Mb[(size_t)idxd * MS32 + we];
            }
            #pragma unroll
            for (int d = 0; d < 32; ++d)
                collo |= ((wreg[d] >> be) & 1u) << d;
        }
        {
            u32 wreg[32];
            #pragma unroll
            for (int d = 0; d < 32; ++d) {
                u32 idxd = (u32)__builtin_amdgcn_readlane((int)idx, d + 32);
                wreg[d] = Mb[(size_t)idxd * MS32 + we];
            }
            #pragma unroll
            for (int d = 0; d < 32; ++d)
                colhi |= ((wreg[d] >> be) & 1u) << d;
        }
        colmL[ch * 64 + lane] = ((u64)colhi << 32) | (u64)collo;
    }
    __syncthreads();   // sord/colmL ready; wave 1's chunk-0 glls drained

    u64 lt = (1ull << lane) - 1ull;    // bits strictly below my candidate slot
    u32 rw = 0;                        // removed word (lane w owns word w)

    int cur = 0;
    for (int c = 0; c < NCHUNK; ++c) {
        // wave 1: stage chunk c+1 rows into the other buffer
        if (wid == 1 && c + 1 < NCHUNK) {
            u32 ridx[16];
            #pragma unroll
            for (int t = 0; t < 16; ++t)
                ridx[t] = sord[(c + 1) * 64 + t * 4 + sub];
            #pragma unroll
            for (int t = 0; t < 16; ++t) {
                const u32* rowp = Mb + (size_t)ridx[t] * MS32 + l16 * 4;
                __builtin_amdgcn_global_load_lds(
                    (const __attribute__((address_space(1))) void*)rowp,
                    (__attribute__((address_space(3))) void*)&rows[cur ^ 1][t * 256],
                    16, 0, 0);
            }
        }
        // wave 0: the serial chain
        if (wid == 0) {
            u32 idx = sord[c * 64 + lane];
            u32 we = idx >> 5;
            u32 be = idx & 31u;
            bool valid = (c * 64 + lane) < NB;

            // pre-suppression: bit idx of removed mask (word we on lane we)
            u32 wv = (u32)__builtin_amdgcn_ds_bpermute((int)(we << 2), (int)rw);
            bool pre = ((wv >> be) & 1u) != 0u;

            u64 col = colmL[c * 64 + lane];

            // exact greedy via ballot rounds (rounds = chain depth)
            u64 act = __ballot(valid && !pre);
            u64 kept = 0;
            while (act) {
                u64 unsafe = __ballot((col & act & lt) != 0ull);
                u64 safe = act & ~unsafe;           // provably greedy-kept
                kept |= safe;
                u64 supp = __ballot((col & safe & lt) != 0ull);
                act &= ~(safe | supp);
            }

            if ((kept >> lane) & 1ull) atomicOr(&kws[we], 1u << be);

            // fold kept rows into removed mask: branchless gated OR
            // (pad words 58..63 are zero in M so lanes 58..63 stay clean)
            if (kept != 0ull) {
                const u32* rbase = &rows[cur][0];
                u32 klo = (u32)kept, khi = (u32)(kept >> 32);
                #pragma unroll
                for (int d = 0; d < 32; ++d)
                    rw |= rbase[d * 64 + lane] & (0u - ((klo >> d) & 1u));
                #pragma unroll
                for (int d = 0; d < 32; ++d)
                    rw |= rbase[(d + 32) * 64 + lane] & (0u - ((khi >> d) & 1u));
            }
        }
        __syncthreads();   // drains wave 1's staging; orders buffer reuse
        cur ^= 1;
    }
    __syncthreads();       // kws final

    // fused finalize: prob[b][n][cls] = keep ? score : 0 (all 4 waves)
    const float* sc = scores + (size_t)bc * NB;
    float* pb = prob + (size_t)b * NB * NC + cls;
    for (int n = tid; n < NB; n += 256) {
        u32 w = kws[n >> 5];
        float v = ((w >> (n & 31)) & 1u) ? sc[n] : 0.0f;
        pb[(size_t)n * NC] = v;
    }
}

// ---------------------------------------------------------------------------
extern "C" void kernel_launch(void* const* d_in, const int* in_sizes, int n_in,
                              void* d_out, int out_size, void* d_ws, size_t ws_size,
                              hipStream_t stream) {
    const float* x = (const float*)d_in[0];        // (16,125,19,19)
    const float* im_info = (const float*)d_in[1];  // (16,2)

    float* prob_out = (float*)d_out;                       // 577600 floats
    float* boxes_out = prob_out + PROB_ELEMS;              // 115520 floats

    // workspace layout (corners/areas DISJOINT from order: sort and iou run
    // concurrently in the fused kernel)
    float* scores = (float*)d_ws;                           // 577600 f32
    u32* order = (u32*)(scores + PROB_ELEMS);               // 577600 u32
    char* mbase = (char*)d_ws + (size_t)2 * PROB_ELEMS * 4;
    u64* M64 = (u64*)mbase;                                 // 16*1805*32 u64 (padded)
    u32* M32 = (u32*)mbase;
    float4* corners = (float4*)(mbase + (size_t)BB * NB * MS64 * 8 + 256);
    float* areas = (float*)(corners + (size_t)BB * NB);     // 28880 f32

    int nthreads = BB * NB;   // 28880
    decode_kernel<<<(nthreads + 255) / 256, 256, 0, stream>>>(
        x, im_info, boxes_out, corners, areas, scores);

    work_kernel<<<NBC + BB * IOUBLK, 512, 0, stream>>>(
        scores, order, corners, areas, M64);

    nms_scan_kernel<<<NBC, 256, 0, stream>>>(order, M32, scores, prob_out);
}

// Round 12
// 145.404 us; speedup vs baseline: 1.2535x; 1.1904x over previous
//
#include <hip/hip_runtime.h>
#include <hip/hip_bf16.h>

typedef unsigned int u32;
typedef unsigned long long u64;
typedef unsigned char u8;

#define BB 16
#define NA 5
#define NC 20
#define HF 19
#define WF 19
#define NPIX 361        // 19*19
#define NB 1805         // NA*NPIX boxes per batch
#define NW32 58         // ceil(1805/32)
#define NW64 29         // ceil(1805/64)
#define MS64 32         // padded M row stride in u64 (256 B rows)
#define MS32 64         // padded M row stride in u32
#define NBC (BB*NC)     // 320 (batch,class) pairs
#define PROB_ELEMS (BB*NB*NC)   // 577600
#define NCHUNK 29       // ceil(NB/64)
#define IOUQ 8
#define IOUG 226        // ceil(NB/IOUQ)
#define IOUBLK 29       // ceil(IOUG/8) blocks per batch in fused kernel

// Exact-equivalence threshold: RN_f32(inter/denom) > 0.45f
//   <=>  (double)inter > MID * (double)denom
// where MID = midpoint(0.45f, nextup(0.45f)) = 0x1.CCCCCDp-2 (exact in f64;
// 25-bit MID x 24-bit denom product is exact; tie rounds-to-even to 0.45f
// which is NOT > 0.45f, matching the strict > here).
#define IOU_MID 0x1.CCCCCDp-2

__constant__ float c_bias[10] = {1.08f, 1.19f, 3.42f, 4.41f, 6.63f,
                                 11.38f, 9.42f, 5.11f, 16.62f, 10.52f};

__device__ __forceinline__ float sigmoidf_(float v) {
    return 1.0f / (1.0f + expf(-v));
}

// ---------------------------------------------------------------------------
// Kernel 1: decode boxes (-> d_out boxes section), corners+areas, scores.
// ---------------------------------------------------------------------------
__global__ __launch_bounds__(256) void decode_kernel(
        const float* __restrict__ x, const float* __restrict__ im_info,
        float* __restrict__ boxes_out, float4* __restrict__ corners,
        float* __restrict__ areas, float* __restrict__ scores) {
    int tid = blockIdx.x * blockDim.x + threadIdx.x;
    if (tid >= BB * NB) return;
    int b = tid / NB;
    int n = tid % NB;
    int a = n / NPIX;
    int r = n % NPIX;
    int gy = r / WF;
    int gx = r % WF;

    const float* xb = x + (size_t)b * 125 * NPIX + r;   // channel stride NPIX
    float tx = xb[(2 * a + 0) * NPIX];
    float ty = xb[(2 * a + 1) * NPIX];
    float tw = xb[(10 + 2 * a) * NPIX];
    float th = xb[(11 + 2 * a) * NPIX];
    float to = xb[(20 + a) * NPIX];

    float sx = sigmoidf_(tx);
    float sy = sigmoidf_(ty);
    float obj = sigmoidf_(to);

    float im_h = im_info[b * 2 + 0];
    float im_w = im_info[b * 2 + 1];

    float bx = ((sx + (float)gx) / (float)WF) * im_w;
    float by = ((sy + (float)gy) / (float)HF) * im_h;
    float bw = ((expf(tw) * c_bias[2 * a + 0]) / (float)WF) * im_w;
    float bh = ((expf(th) * c_bias[2 * a + 1]) / (float)HF) * im_h;

    reinterpret_cast<float4*>(boxes_out)[tid] = make_float4(bx, by, bw, bh);

    // corners exactly as reference computes them from (cx,cy,w,h)
    float x1 = bx - bw * 0.5f, x2 = bx + bw * 0.5f;
    float y1 = by - bh * 0.5f, y2 = by + bh * 0.5f;
    corners[tid] = make_float4(x1, y1, x2, y2);
    areas[tid] = bw * bh;

    // softmax over 20 classes * obj  -> scores[(b*NC + c)*NB + n]
    float cv[NC];
    float m = -1e30f;
    #pragma unroll
    for (int c = 0; c < NC; ++c) {
        cv[c] = xb[(25 + NC * a + c) * NPIX];
        m = fmaxf(m, cv[c]);
    }
    float sum = 0.0f;
    #pragma unroll
    for (int c = 0; c < NC; ++c) {
        cv[c] = expf(cv[c] - m);
        sum += cv[c];
    }
    #pragma unroll
    for (int c = 0; c < NC; ++c) {
        scores[((size_t)b * NC + c) * NB + n] = (cv[c] / sum) * obj;
    }
}

// ---------------------------------------------------------------------------
// Fused kernel 2: blocks [0, NBC) run the bitonic argsort; blocks
// [NBC, NBC + BB*IOUBLK) run the IoU bitmask.
// IoU exploits EXACT SYMMETRY (min/max/mul/add commutative in f32, so
// IoU(i,j) is bit-identical to IoU(j,i)): each 8-row group only computes
// column blocks t >= its own block Bg; mirrored entries produced by
// byte-granular transpose stores (disjoint bytes — no races).
// ---------------------------------------------------------------------------
__device__ __forceinline__ u64 shfl_xor_u64(u64 v, int m) {
    u32 lo = (u32)v, hi = (u32)(v >> 32);
    lo = (u32)__shfl_xor((int)lo, m, 64);
    hi = (u32)__shfl_xor((int)hi, m, 64);
    return ((u64)hi << 32) | lo;
}

__device__ void sort_body(const float* __restrict__ scores,
                          u32* __restrict__ order, int bc) {
    __shared__ u64 keys[2048];
    const float* s = scores + (size_t)bc * NB;
    int tid = threadIdx.x;
    int lane = tid & 63;
    int w = tid >> 6;
    int base = w * 256;

    u64 r[4];
    #pragma unroll
    for (int i = 0; i < 4; ++i) {
        int e = base + i * 64 + lane;
        u64 k = 0;
        if (e < NB) {
            u32 sb = __float_as_uint(s[e]);
            k = ((u64)sb << 32) | (u64)(2047 - e);
        }
        r[i] = k;
    }

    auto rexch = [&](int k, int ia, int ib) {
        int e = base + ia * 64 + lane;           // lower element index
        bool desc = ((e & k) == 0);
        u64 a = r[ia], b = r[ib];
        u64 mx = a > b ? a : b, mn = a > b ? b : a;
        r[ia] = desc ? mx : mn;
        r[ib] = desc ? mn : mx;
    };
    auto shstage = [&](int k, int j) {
        #pragma unroll
        for (int i = 0; i < 4; ++i) {
            int e = base + i * 64 + lane;
            u64 p = shfl_xor_u64(r[i], j);
            bool desc = ((e & k) == 0);
            bool upper = (lane & j) != 0;
            bool takemax = desc ^ upper;
            u64 a = r[i];
            u64 mx = a > p ? a : p, mn = a > p ? p : a;
            r[i] = takemax ? mx : mn;
        }
    };
    auto regsession = [&](int k) {
        if (k >= 256) { rexch(k, 0, 2); rexch(k, 1, 3); }   // j=128
        if (k >= 128) { rexch(k, 0, 1); rexch(k, 2, 3); }   // j=64
        int j0 = (k <= 64) ? (k >> 1) : 32;
        for (int j = j0; j >= 1; j >>= 1) shstage(k, j);
    };
    auto store_regs = [&]() {
        #pragma unroll
        for (int i = 0; i < 4; ++i) keys[base + i * 64 + lane] = r[i];
    };
    auto load_regs = [&]() {
        #pragma unroll
        for (int i = 0; i < 4; ++i) r[i] = keys[base + i * 64 + lane];
    };
    auto ldspass = [&](int k, int j) {
        #pragma unroll
        for (int h = 0; h < 2; ++h) {
            int m = tid + h * 512;
            int i1 = (m / j) * 2 * j + (m % j);
            int i2 = i1 + j;
            u64 a = keys[i1], b = keys[i2];
            bool desc = ((i1 & k) == 0);
            bool sw = desc ? (a < b) : (a > b);
            if (sw) { keys[i1] = b; keys[i2] = a; }
        }
        __syncthreads();
    };

    for (int k = 2; k <= 256; k <<= 1) regsession(k);
    store_regs(); __syncthreads();

    ldspass(512, 256);
    load_regs(); regsession(512);
    store_regs(); __syncthreads();

    ldspass(1024, 512); ldspass(1024, 256);
    load_regs(); regsession(1024);
    store_regs(); __syncthreads();

    ldspass(2048, 1024); ldspass(2048, 512); ldspass(2048, 256);
    load_regs(); regsession(2048);

    #pragma unroll
    for (int i = 0; i < 4; ++i) {
        int e = base + i * 64 + lane;
        if (e < NB)
            order[(size_t)bc * NB + e] = 2047u - (u32)(r[i] & 0xFFFFFFFFull);
    }
}

__device__ void iou_body(const float4* __restrict__ corners,
                         const float* __restrict__ areas,
                         u64* __restrict__ M64, int b, int i0) {
    int lane = threadIdx.x & 63;
    const float4* cb = corners + (size_t)b * NB;
    const float* ab = areas + (size_t)b * NB;
    int Bg = i0 >> 6;                  // this group's column block (triangle)
    int byteoff = (i0 & 63) >> 3;      // byte slot of this 8-row group
    u8* M8 = (u8*)M64;

    float4 cr[IOUQ];
    float arr[IOUQ];
    #pragma unroll
    for (int q = 0; q < IOUQ; ++q) {
        int iq = i0 + q < NB ? i0 + q : NB - 1;
        cr[q] = cb[iq];
        arr[q] = ab[iq];
    }

    u64 word[IOUQ] = {0, 0, 0, 0, 0, 0, 0, 0};
    // software-pipelined column loads (depth 1), t starts at Bg (triangle)
    int jp = Bg * 64 + lane;
    int jpc = jp < NB ? jp : NB - 1;
    float4 cj = cb[jpc];
    float ar = ab[jpc];
    for (int t = Bg; t < NW64; ++t) {
        int j = t * 64 + lane;
        float4 cjn = cj;
        float arn = ar;
        if (t + 1 < NW64) {
            int j2 = (t + 1) * 64 + lane;
            int jc2 = j2 < NB ? j2 : NB - 1;
            cjn = cb[jc2];
            arn = ab[jc2];
        }
        u64 mv[IOUQ];
        #pragma unroll
        for (int q = 0; q < IOUQ; ++q) {
            float iw = fmaxf(fminf(cr[q].z, cj.z) - fmaxf(cr[q].x, cj.x), 0.0f);
            float ih = fmaxf(fminf(cr[q].w, cj.w) - fmaxf(cr[q].y, cj.y), 0.0f);
            float in = iw * ih;
            float dn = arr[q] + ar - in + 1e-9f;
            bool p = ((double)in > IOU_MID * (double)dn) && (j < NB);
            u64 m = __ballot(p);
            mv[q] = m;
            if (lane == t) word[q] = m;
        }
        // mirror: byte for row j's word Bg (bits q = this group's 8 rows).
        if (t > Bg && j < NB) {
            u32 byt = 0;
            #pragma unroll
            for (int q = 0; q < IOUQ; ++q)
                byt |= ((u32)((mv[q] >> lane) & 1ull)) << q;
            M8[(((size_t)b * NB + j) * MS64 + Bg) * 8 + byteoff] = (u8)byt;
        }
        cj = cjn;
        ar = arn;
    }
    // direct writes: words [Bg..28] values, [29..31] zero; words < Bg are
    // owned by other groups' mirror bytes.
    if (lane >= Bg && lane < MS64) {
        #pragma unroll
        for (int q = 0; q < IOUQ; ++q) {
            int iq = i0 + q;
            if (iq < NB) {
                u64 w = (lane < NW64) ? word[q] : 0ull;
                M64[((size_t)b * NB + iq) * MS64 + lane] = w;
            }
        }
    }
}

__global__ __launch_bounds__(512) void work_kernel(
        const float* __restrict__ scores, u32* __restrict__ order,
        const float4* __restrict__ corners, const float* __restrict__ areas,
        u64* __restrict__ M64) {
    int blk = blockIdx.x;
    if (blk < NBC) {
        sort_body(scores, order, blk);
    } else {
        int ib = blk - NBC;            // 0 .. BB*IOUBLK-1
        int b = ib / IOUBLK;
        int gset = ib % IOUBLK;
        int wid = threadIdx.x >> 6;
        int group = gset * 8 + wid;    // 8 row-groups per block
        if (group < IOUG) iou_body(corners, areas, M64, b, group * IOUQ);
    }
}

// ---------------------------------------------------------------------------
// Kernel 3: greedy NMS + prob write, one block (4 waves) per (b,c).
// 3-stage software pipeline, one barrier per chunk (NO global colmask
// gather — the TA-bound scattered prepass is gone):
//   wave 1: stage chunk c+2 rows -> LDS buf[(c+2)%3]  (width-16 gll)
//   waves 2/3: bit-transpose chunk c+1 colmask FROM THE STAGED LDS ROWS
//              (wave2: bits 0..31, wave3: bits 32..63; 32 ds_reads each)
//   wave 0: serial chain on chunk c: bpermute pre-check -> exact greedy
//           ballot rounds -> gated-OR fold from buf[c%3] (skip if kept==0)
// Epilogue: all 4 waves write prob[b][n][cls] from LDS keep bits.
// blockIdx: b = blk % 16 clusters same-batch blocks per XCD (M L2 locality).
// ---------------------------------------------------------------------------
__global__ __launch_bounds__(256) void nms_scan_kernel(
        const u32* __restrict__ order, const u32* __restrict__ M32,
        const float* __restrict__ scores, float* __restrict__ prob) {
    int blk = blockIdx.x;
    int b = blk % BB;            // blk%8 = XCD -> 2 batches per XCD
    int cls = blk / BB;
    int bc = b * NC + cls;
    int tid = threadIdx.x;
    int wid = tid >> 6;
    int lane = tid & 63;
    const u32* ord = order + (size_t)bc * NB;
    const u32* Mb = M32 + (size_t)b * NB * MS32;

    __shared__ u32 rows[3][64 * 64];   // [buf][row d][word], 48 KB
    __shared__ u32 sord[NCHUNK * 64];  // 1856 sorted indices (clamped), 7.4 KB
    __shared__ u32 colmS[2][2][64];    // [parity][lo/hi][lane], 1 KB
    __shared__ u32 kws[64];
    if (tid < 64) kws[tid] = 0;

    for (int t = tid; t < NCHUNK * 64; t += 256)
        sord[t] = (t < NB) ? ord[t] : (u32)(NB - 1);
    __syncthreads();

    int sub = lane >> 4;               // row-within-group for staging
    int l16 = lane & 15;

    // staging helper pattern (wave 1): 16 idx ds_reads + 16 width-16 glls
    #define STAGE_CHUNK(CH, BUF)                                              \
        do {                                                                  \
            u32 ridx[16];                                                     \
            _Pragma("unroll")                                                 \
            for (int t = 0; t < 16; ++t)                                      \
                ridx[t] = sord[(CH) * 64 + t * 4 + sub];                      \
            _Pragma("unroll")                                                 \
            for (int t = 0; t < 16; ++t) {                                    \
                const u32* rowp = Mb + (size_t)ridx[t] * MS32 + l16 * 4;      \
                __builtin_amdgcn_global_load_lds(                             \
                    (const __attribute__((address_space(1))) void*)rowp,      \
                    (__attribute__((address_space(3))) void*)                 \
                        &rows[BUF][t * 256],                                  \
                    16, 0, 0);                                                \
            }                                                                 \
        } while (0)

    // prologue: stage chunk 0; then stage chunk 1 + colmask chunk 0
    if (wid == 1) STAGE_CHUNK(0, 0);
    __syncthreads();                   // drain chunk-0 staging
    if (wid == 1 && NCHUNK > 1) STAGE_CHUNK(1, 1);
    if (wid >= 2) {
        u32 idx = sord[lane];
        u32 we = idx >> 5, be = idx & 31u;
        const u32* rb = &rows[0][0];
        int dbase = (wid == 2) ? 0 : 32;
        u32 acc = 0;
        #pragma unroll
        for (int d = 0; d < 32; ++d) {
            u32 w = rb[(dbase + d) * 64 + we];
            acc |= ((w >> be) & 1u) << d;
        }
        colmS[0][wid - 2][lane] = acc;
    }
    __syncthreads();                   // colm[0] ready; chunk-1 glls drained

    u64 lt = (1ull << lane) - 1ull;    // bits strictly below my candidate slot
    u32 rw = 0;                        // removed word (lane w owns word w)

    for (int c = 0; c < NCHUNK; ++c) {
        // wave 1: stage chunk c+2
        if (wid == 1 && c + 2 < NCHUNK) STAGE_CHUNK(c + 2, (c + 2) % 3);

        // waves 2/3: colmask of chunk c+1 from its staged LDS rows
        if (wid >= 2 && c + 1 < NCHUNK) {
            u32 idx = sord[(c + 1) * 64 + lane];
            u32 we = idx >> 5, be = idx & 31u;
            const u32* rb = &rows[(c + 1) % 3][0];
            int dbase = (wid == 2) ? 0 : 32;
            u32 acc = 0;
            #pragma unroll
            for (int d = 0; d < 32; ++d) {
                u32 w = rb[(dbase + d) * 64 + we];
                acc |= ((w >> be) & 1u) << d;
            }
            colmS[(c + 1) & 1][wid - 2][lane] = acc;
        }

        // wave 0: the serial chain on chunk c
        if (wid == 0) {
            u32 idx = sord[c * 64 + lane];
            u32 we = idx >> 5;
            u32 be = idx & 31u;
            bool valid = (c * 64 + lane) < NB;

            // pre-suppression: bit idx of removed mask (word we on lane we)
            u32 wv = (u32)__builtin_amdgcn_ds_bpermute((int)(we << 2), (int)rw);
            bool pre = ((wv >> be) & 1u) != 0u;

            u64 col = ((u64)colmS[c & 1][1][lane] << 32)
                    | (u64)colmS[c & 1][0][lane];

            // exact greedy via ballot rounds (rounds = chain depth)
            u64 act = __ballot(valid && !pre);
            u64 kept = 0;
            while (act) {
                u64 unsafe = __ballot((col & act & lt) != 0ull);
                u64 safe = act & ~unsafe;           // provably greedy-kept
                kept |= safe;
                u64 supp = __ballot((col & safe & lt) != 0ull);
                act &= ~(safe | supp);
            }

            if ((kept >> lane) & 1ull) atomicOr(&kws[we], 1u << be);

            // fold kept rows into removed mask: branchless gated OR
            // (pad words 58..63 are zero in M so lanes 58..63 stay clean)
            if (kept != 0ull) {
                const u32* rbase = &rows[c % 3][0];
                u32 klo = (u32)kept, khi = (u32)(kept >> 32);
                #pragma unroll
                for (int d = 0; d < 32; ++d)
                    rw |= rbase[d * 64 + lane] & (0u - ((klo >> d) & 1u));
                #pragma unroll
                for (int d = 0; d < 32; ++d)
                    rw |= rbase[(d + 32) * 64 + lane] & (0u - ((khi >> d) & 1u));
            }
        }
        __syncthreads();   // drains staging; orders colm/rows reuse
    }
    #undef STAGE_CHUNK

    // fused finalize: prob[b][n][cls] = keep ? score : 0 (all 4 waves)
    const float* sc = scores + (size_t)bc * NB;
    float* pb = prob + (size_t)b * NB * NC + cls;
    for (int n = tid; n < NB; n += 256) {
        u32 w = kws[n >> 5];
        float v = ((w >> (n & 31)) & 1u) ? sc[n] : 0.0f;
        pb[(size_t)n * NC] = v;
    }
}

// ---------------------------------------------------------------------------
extern "C" void kernel_launch(void* const* d_in, const int* in_sizes, int n_in,
                              void* d_out, int out_size, void* d_ws, size_t ws_size,
                              hipStream_t stream) {
    const float* x = (const float*)d_in[0];        // (16,125,19,19)
    const float* im_info = (const float*)d_in[1];  // (16,2)

    float* prob_out = (float*)d_out;                       // 577600 floats
    float* boxes_out = prob_out + PROB_ELEMS;              // 115520 floats

    // workspace layout (corners/areas DISJOINT from order: sort and iou run
    // concurrently in the fused kernel)
    float* scores = (float*)d_ws;                           // 577600 f32
    u32* order = (u32*)(scores + PROB_ELEMS);               // 577600 u32
    char* mbase = (char*)d_ws + (size_t)2 * PROB_ELEMS * 4;
    u64* M64 = (u64*)mbase;                                 // 16*1805*32 u64 (padded)
    u32* M32 = (u32*)mbase;
    float4* corners = (float4*)(mbase + (size_t)BB * NB * MS64 * 8 + 256);
    float* areas = (float*)(corners + (size_t)BB * NB);     // 28880 f32

    int nthreads = BB * NB;   // 28880
    decode_kernel<<<(nthreads + 255) / 256, 256, 0, stream>>>(
        x, im_info, boxes_out, corners, areas, scores);

    work_kernel<<<NBC + BB * IOUBLK, 512, 0, stream>>>(
        scores, order, corners, areas, M64);

    nms_scan_kernel<<<NBC, 256, 0, stream>>>(order, M32, scores, prob_out);
}